// Round 1
// baseline (161.990 us; speedup 1.0000x reference)
//
#include <hip/hip_runtime.h>
#include <math.h>

// 18-qubit statevector simulator, 2 circuits + overlap.
// Qubit q in the reference maps to index bit (17-q). CZ chain is diagonal:
// sign = parity(popcount(i & (i>>1) & 0x1FFFF)).
//
// Per layer, fused U_q = RZ*RY*RX (2x2 complex, composed in fp64 in setup).
// 7 LDS passes total (one layer per pass in steady state), alternating local
// bit-sets A={0..10} and B={0..3}u{11..17}; each pass applies the previous
// layer's leftover gates, the diagonal CZ, then the next layer's gates on its
// local set.

#define NQ      18
#define NSTATE  (1 << NQ)
#define LAYERS  6
#define SLOC    11
#define NL      (1 << SLOC)      // 2048 amps per chunk
#define NPAIR   (NL / 2)         // 1024 pairs per gate
#define TPB     256
#define NCHUNK  (NSTATE / NL)    // 128 chunks per circuit

// ---------------- setup: compose U = RZ*RY*RX per (circuit, layer, qubit) ---
__global__ __launch_bounds__(256) void setup_kernel(
    const float* __restrict__ x1, const float* __restrict__ x2,
    const float* __restrict__ iscale, const float* __restrict__ var,
    float2* __restrict__ U)
{
    int tid = threadIdx.x;
    if (tid >= 2 * LAYERS * NQ) return;
    int c = tid / (LAYERS * NQ);
    int rem = tid % (LAYERS * NQ);
    int l = rem / NQ, q = rem % NQ;
    const float* x = c ? x2 : x1;
    double tx = (double)iscale[l * NQ + q] * (double)x[q];
    double ty = (double)var[l * 2 * NQ + q];
    double tz = (double)var[l * 2 * NQ + NQ + q];
    double cx = cos(tx * 0.5), sx = sin(tx * 0.5);
    double cy = cos(ty * 0.5), sy = sin(ty * 0.5);
    // M = RY * RX
    double m00r = cy * cx,  m00i =  sy * sx;
    double m01r = -sy * cx, m01i = -cy * sx;
    double m10r = sy * cx,  m10i = -cy * sx;
    double m11r = cy * cx,  m11i = -sy * sx;
    double zc = cos(tz * 0.5), zs = sin(tz * 0.5);
    // U = RZ * M : row0 *= (zc - i zs), row1 *= (zc + i zs)
    double u00r = m00r * zc + m00i * zs, u00i = m00i * zc - m00r * zs;
    double u01r = m01r * zc + m01i * zs, u01i = m01i * zc - m01r * zs;
    double u10r = m10r * zc - m10i * zs, u10i = m10i * zc + m10r * zs;
    double u11r = m11r * zc - m11i * zs, u11i = m11i * zc + m11r * zs;
    float2* up = U + tid * 4;
    up[0] = make_float2((float)u00r, (float)u00i);
    up[1] = make_float2((float)u01r, (float)u01i);
    up[2] = make_float2((float)u10r, (float)u10i);
    up[3] = make_float2((float)u11r, (float)u11i);
}

// ---------------- one pass: stage chunk in LDS, apply gates ----------------
__global__ __launch_bounds__(TPB) void pass_kernel(
    float2* __restrict__ states, const float2* __restrict__ U,
    int setB, int prev_layer, unsigned prev_mask, int do_cz,
    int next_layer, unsigned next_mask, int do_init)
{
    __shared__ float sre[NL];
    __shared__ float sim[NL];
    int blk  = blockIdx.x;
    int circ = blk >> 7;         // 128 chunks per circuit
    int g    = blk & (NCHUNK - 1);
    float2* st = states + (size_t)circ * NSTATE;
    int t = threadIdx.x;

    // local index L -> global statevector index
    // set A: gi = (g<<11) | L              (local bits = global bits 0..10)
    // set B: gi = ((L>>4)<<11)|(g<<4)|(L&15) (local bits 0..3 -> global 0..3,
    //                                         local bits 4..10 -> global 11..17)
    auto gidx = [&](int L) -> int {
        return setB ? ((((L >> 4) << 11) | (g << 4)) | (L & 15))
                    : ((g << 11) | L);
    };

    if (do_init) {
        for (int k = 0; k < NL / TPB; ++k) {
            int L = t + k * TPB;
            sre[L] = (gidx(L) == 0) ? 1.0f : 0.0f;
            sim[L] = 0.0f;
        }
    } else {
        for (int k = 0; k < NL / TPB; ++k) {
            int L = t + k * TPB;
            float2 a = st[gidx(L)];
            sre[L] = a.x; sim[L] = a.y;
        }
    }
    __syncthreads();

    const float2* Ub = U + (size_t)circ * (LAYERS * NQ * 4);

    auto apply_gates = [&](int layer, unsigned mask) {
        for (int j = 0; j < SLOC; ++j) {
            if (!((mask >> j) & 1u)) continue;
            int gb = setB ? (j < 4 ? j : j + 7) : j;   // global bit
            int q  = 17 - gb;                          // reference qubit index
            const float2* up = Ub + ((size_t)layer * NQ + q) * 4;
            float u00r = up[0].x, u00i = up[0].y;
            float u01r = up[1].x, u01i = up[1].y;
            float u10r = up[2].x, u10i = up[2].y;
            float u11r = up[3].x, u11i = up[3].y;
            for (int k = 0; k < NPAIR / TPB; ++k) {
                int p  = t + k * TPB;
                int i0 = ((p >> j) << (j + 1)) | (p & ((1 << j) - 1));
                int i1 = i0 | (1 << j);
                float a0r = sre[i0], a0i = sim[i0];
                float a1r = sre[i1], a1i = sim[i1];
                float n0r = u00r * a0r - u00i * a0i + u01r * a1r - u01i * a1i;
                float n0i = u00r * a0i + u00i * a0r + u01r * a1i + u01i * a1r;
                float n1r = u10r * a0r - u10i * a0i + u11r * a1r - u11i * a1i;
                float n1i = u10r * a0i + u10i * a0r + u11r * a1i + u11i * a1r;
                sre[i0] = n0r; sim[i0] = n0i;
                sre[i1] = n1r; sim[i1] = n1i;
            }
            __syncthreads();
        }
    };

    if (prev_layer >= 0) apply_gates(prev_layer, prev_mask);

    if (do_cz) {
        for (int k = 0; k < NL / TPB; ++k) {
            int L  = t + k * TPB;
            int gi = gidx(L);
            if (__popc(gi & (gi >> 1) & 0x1FFFF) & 1) {
                sre[L] = -sre[L]; sim[L] = -sim[L];
            }
        }
        __syncthreads();
    }

    if (next_layer >= 0) apply_gates(next_layer, next_mask);

    for (int k = 0; k < NL / TPB; ++k) {
        int L = t + k * TPB;
        st[gidx(L)] = make_float2(sre[L], sim[L]);
    }
}

// ---------------- overlap reduction ----------------------------------------
__global__ __launch_bounds__(256) void reduce1(
    const float2* __restrict__ states, double2* __restrict__ partials)
{
    __shared__ double sr[256];
    __shared__ double si[256];
    int t = threadIdx.x;
    int base = blockIdx.x * 2048;
    const float2* s1 = states;            // psi1 (from x1)
    const float2* s2 = states + NSTATE;   // psi2 (from x2)
    double ar = 0.0, ai = 0.0;
    for (int k = 0; k < 8; ++k) {
        int i = base + t + k * 256;
        float2 p1 = s1[i], p2 = s2[i];
        // conj(p2) * p1
        ar += (double)p2.x * p1.x + (double)p2.y * p1.y;
        ai += (double)p2.x * p1.y - (double)p2.y * p1.x;
    }
    sr[t] = ar; si[t] = ai;
    __syncthreads();
    for (int ofs = 128; ofs > 0; ofs >>= 1) {
        if (t < ofs) { sr[t] += sr[t + ofs]; si[t] += si[t + ofs]; }
        __syncthreads();
    }
    if (t == 0) {
        double2 v; v.x = sr[0]; v.y = si[0];
        partials[blockIdx.x] = v;
    }
}

__global__ __launch_bounds__(128) void reduce2(
    const double2* __restrict__ partials, float* __restrict__ out)
{
    __shared__ double sr[128];
    __shared__ double si[128];
    int t = threadIdx.x;
    double2 v = partials[t];
    sr[t] = v.x; si[t] = v.y;
    __syncthreads();
    for (int ofs = 64; ofs > 0; ofs >>= 1) {
        if (t < ofs) { sr[t] += sr[t + ofs]; si[t] += si[t + ofs]; }
        __syncthreads();
    }
    if (t == 0) out[0] = (float)(sr[0] * sr[0] + si[0] * si[0]);
}

// ---------------- launch ----------------------------------------------------
extern "C" void kernel_launch(void* const* d_in, const int* in_sizes, int n_in,
                              void* d_out, int out_size, void* d_ws, size_t ws_size,
                              hipStream_t stream)
{
    const float* x1 = (const float*)d_in[0];
    const float* x2 = (const float*)d_in[1];
    const float* iscale = (const float*)d_in[2];
    const float* var = (const float*)d_in[3];
    float* out = (float*)d_out;

    // ws layout: [0, 6912) U matrices; [8192, 10240) partials (128 double2);
    // [16384, 16384+4MB) the two statevectors.
    float2*  U        = (float2*)d_ws;
    double2* partials = (double2*)((char*)d_ws + 8192);
    float2*  states   = (float2*)((char*)d_ws + 16384);

    setup_kernel<<<1, 256, 0, stream>>>(x1, x2, iscale, var, U);

    const unsigned MASK_FULL = 0x7FFu;  // local bits 0..10
    const unsigned MASK_HI   = 0x7F0u;  // local bits 4..10 (the leftover set)
    dim3 grid(2 * NCHUNK), block(TPB);

    // P0: set A, init, layer0 on global bits 0..10
    pass_kernel<<<grid, block, 0, stream>>>(states, U, 0, -1, 0u, 0, 0, MASK_FULL, 1);
    // P1: set B: layer0 leftover (global 11..17), CZ0, layer1 on B
    pass_kernel<<<grid, block, 0, stream>>>(states, U, 1, 0, MASK_HI, 1, 1, MASK_FULL, 0);
    // P2: set A: layer1 leftover (global 4..10), CZ1, layer2 on A
    pass_kernel<<<grid, block, 0, stream>>>(states, U, 0, 1, MASK_HI, 1, 2, MASK_FULL, 0);
    // P3: set B
    pass_kernel<<<grid, block, 0, stream>>>(states, U, 1, 2, MASK_HI, 1, 3, MASK_FULL, 0);
    // P4: set A
    pass_kernel<<<grid, block, 0, stream>>>(states, U, 0, 3, MASK_HI, 1, 4, MASK_FULL, 0);
    // P5: set B
    pass_kernel<<<grid, block, 0, stream>>>(states, U, 1, 4, MASK_HI, 1, 5, MASK_FULL, 0);
    // P6: set A: layer5 leftover (global 4..10), CZ5, done
    pass_kernel<<<grid, block, 0, stream>>>(states, U, 0, 5, MASK_HI, 1, -1, 0u, 0);

    reduce1<<<NSTATE / 2048, 256, 0, stream>>>(states, partials);
    reduce2<<<1, 128, 0, stream>>>(partials, out);
}

// Round 2
// 138.401 us; speedup vs baseline: 1.1704x; 1.1704x over previous
//
#include <hip/hip_runtime.h>
#include <math.h>

// 18-qubit statevector, 2 circuits + |<psi2|psi1>|^2.
// Qubit q (reference) <-> index bit (17-q). CZ chain diagonal:
// sign = parity(popc(i & (i>>1) & 0x1FFFF)).
//
// Register-blocked passes: per pass, 7 "sweeps"; each sweep a thread holds
// 8 amps (3 local bits) in VGPRs and applies up to 3 gates in registers ->
// one LDS round-trip per <=3 gates. CZ folded into registers. XOR bank
// swizzle on LDS index. 7 passes alternate local sets A={0..10} and
// B={0..3}u{11..17}; each pass: prev layer's 7 leftover gates, CZ, next
// layer's 11 gates.

#define NQ      18
#define NSTATE  (1 << NQ)
#define LAYERS  6
#define SLOC    11
#define NL      (1 << SLOC)      // 2048 amps per chunk
#define TPB     256
#define NCHUNK  (NSTATE / NL)    // 128 chunks per circuit

__device__ __forceinline__ int SW(int i) { return i ^ ((i >> 5) & 31); }

// ---------------- setup: compose U = RZ*RY*RX per (circuit, layer, qubit) ---
__global__ __launch_bounds__(256) void setup_kernel(
    const float* __restrict__ x1, const float* __restrict__ x2,
    const float* __restrict__ iscale, const float* __restrict__ var,
    float2* __restrict__ U)
{
    int tid = threadIdx.x;
    if (tid >= 2 * LAYERS * NQ) return;
    int c = tid / (LAYERS * NQ);
    int rem = tid % (LAYERS * NQ);
    int l = rem / NQ, q = rem % NQ;
    const float* x = c ? x2 : x1;
    double tx = (double)iscale[l * NQ + q] * (double)x[q];
    double ty = (double)var[l * 2 * NQ + q];
    double tz = (double)var[l * 2 * NQ + NQ + q];
    double cx = cos(tx * 0.5), sx = sin(tx * 0.5);
    double cy = cos(ty * 0.5), sy = sin(ty * 0.5);
    double m00r = cy * cx,  m00i =  sy * sx;
    double m01r = -sy * cx, m01i = -cy * sx;
    double m10r = sy * cx,  m10i = -cy * sx;
    double m11r = cy * cx,  m11i = -sy * sx;
    double zc = cos(tz * 0.5), zs = sin(tz * 0.5);
    double u00r = m00r * zc + m00i * zs, u00i = m00i * zc - m00r * zs;
    double u01r = m01r * zc + m01i * zs, u01i = m01i * zc - m01r * zs;
    double u10r = m10r * zc - m10i * zs, u10i = m10i * zc + m10r * zs;
    double u11r = m11r * zc - m11i * zs, u11i = m11i * zc + m11r * zs;
    float2* up = U + tid * 4;
    up[0] = make_float2((float)u00r, (float)u00i);
    up[1] = make_float2((float)u01r, (float)u01i);
    up[2] = make_float2((float)u10r, (float)u10i);
    up[3] = make_float2((float)u11r, (float)u11i);
}

// Apply one 1q gate to 8 register amps; pairs differ in reg bit JB (1,2,4).
template<int JB>
__device__ __forceinline__ void apply_gate(float (&ar)[8], float (&ai)[8],
                                           const float2* __restrict__ up)
{
    float u00r = up[0].x, u00i = up[0].y, u01r = up[1].x, u01i = up[1].y;
    float u10r = up[2].x, u10i = up[2].y, u11r = up[3].x, u11i = up[3].y;
#pragma unroll
    for (int r = 0; r < 8; ++r) {
        if (r & JB) continue;
        int r1 = r | JB;
        float a0r = ar[r], a0i = ai[r], a1r = ar[r1], a1i = ai[r1];
        ar[r]  = u00r * a0r - u00i * a0i + u01r * a1r - u01i * a1i;
        ai[r]  = u00r * a0i + u00i * a0r + u01r * a1i + u01i * a1r;
        ar[r1] = u10r * a0r - u10i * a0i + u11r * a1r - u11i * a1i;
        ai[r1] = u10r * a0i + u10i * a0r + u11r * a1i + u11i * a1r;
    }
}

// ---------------- one pass ----------------
__global__ __launch_bounds__(TPB) void pass_kernel(
    float2* __restrict__ states, const float2* __restrict__ U,
    int setB, int prev_layer, int do_cz, int next_layer, int do_init,
    double* __restrict__ acc, unsigned* __restrict__ cnt, int zero_acc)
{
    __shared__ float sre[NL];
    __shared__ float sim[NL];
    int blk  = blockIdx.x;
    int circ = blk >> 7;
    int g    = blk & (NCHUNK - 1);
    float2* st = states + (size_t)circ * NSTATE;
    int t = threadIdx.x;

    if (zero_acc && blk == 0 && t == 0) { acc[0] = 0.0; acc[1] = 0.0; *cnt = 0u; }

    // local idx L -> global statevector idx
    auto gidx = [&](int L) -> int {
        return setB ? ((((L >> 4) << 11) | (g << 4)) | (L & 15))
                    : ((g << 11) | L);
    };

    if (do_init) {
#pragma unroll
        for (int k = 0; k < NL / TPB; ++k) {
            int L = t + k * TPB;
            int p = SW(L);
            sre[p] = (gidx(L) == 0) ? 1.0f : 0.0f;
            sim[p] = 0.0f;
        }
    } else {
        const float4* g4 = (const float4*)st;
#pragma unroll
        for (int k = 0; k < NL / (2 * TPB); ++k) {
            int L = 2 * (t + k * TPB);
            float4 v = g4[gidx(L) >> 1];
            int p0 = SW(L), p1 = SW(L + 1);
            sre[p0] = v.x; sim[p0] = v.y;
            sre[p1] = v.z; sim[p1] = v.w;
        }
    }
    __syncthreads();

    const float2* Ub = U + (size_t)circ * (LAYERS * NQ * 4);
    // gate-matrix pointer for a gate on local bit s of given layer
    auto gp = [&](int layer, int s) -> const float2* {
        int gb = setB ? (s < 4 ? s : s + 7) : s;
        return Ub + ((size_t)layer * NQ + (17 - gb)) * 4;
    };

    // one sweep: 3 local bits s0<s1<s2 held in registers; gates g0/g1/g2
    // (nullptr = skip) act on those bits; optional CZ sign fold.
    auto sweep = [&](int s0, int s1, int s2, const float2* g0,
                     const float2* g1, const float2* g2, bool fold_cz) {
        int lo = t & ((1 << s0) - 1);
        int m1 = (t >> s0) & ((1 << (s1 - s0 - 1)) - 1);
        int m2 = (t >> (s1 - 1)) & ((1 << (s2 - s1 - 1)) - 1);
        int hi = t >> (s2 - 2);
        int base = lo | (m1 << (s0 + 1)) | (m2 << (s1 + 1)) | (hi << (s2 + 1));
        int idx[8];
#pragma unroll
        for (int r = 0; r < 8; ++r)
            idx[r] = base | ((r & 1) << s0) | (((r >> 1) & 1) << s1)
                          | (((r >> 2) & 1) << s2);
        float ar[8], ai[8];
#pragma unroll
        for (int r = 0; r < 8; ++r) {
            int p = SW(idx[r]);
            ar[r] = sre[p]; ai[r] = sim[p];
        }
        if (g0) apply_gate<1>(ar, ai, g0);
        if (g1) apply_gate<2>(ar, ai, g1);
        if (g2) apply_gate<4>(ar, ai, g2);
        if (fold_cz) {
#pragma unroll
            for (int r = 0; r < 8; ++r) {
                int gi = gidx(idx[r]);
                if (__popc(gi & (gi >> 1) & 0x1FFFF) & 1) {
                    ar[r] = -ar[r]; ai[r] = -ai[r];
                }
            }
        }
#pragma unroll
        for (int r = 0; r < 8; ++r) {
            int p = SW(idx[r]);
            sre[p] = ar[r]; sim[p] = ai[r];
        }
        __syncthreads();
    };

    if (prev_layer >= 0) {
        int pl = prev_layer;
        sweep(4, 5, 6,  gp(pl, 4), gp(pl, 5), gp(pl, 6), false);
        sweep(7, 8, 9,  gp(pl, 7), gp(pl, 8), gp(pl, 9), false);
        sweep(0, 1, 10, nullptr,   nullptr,   gp(pl, 10), do_cz != 0);
    }
    if (next_layer >= 0) {
        int nl2 = next_layer;
        sweep(0, 1, 2,  gp(nl2, 0), gp(nl2, 1), gp(nl2, 2), false);
        sweep(3, 4, 5,  gp(nl2, 3), gp(nl2, 4), gp(nl2, 5), false);
        sweep(6, 7, 8,  gp(nl2, 6), gp(nl2, 7), gp(nl2, 8), false);
        sweep(0, 9, 10, nullptr,    gp(nl2, 9), gp(nl2, 10), false);
    }

    float4* g4o = (float4*)st;
#pragma unroll
    for (int k = 0; k < NL / (2 * TPB); ++k) {
        int L = 2 * (t + k * TPB);
        int p0 = SW(L), p1 = SW(L + 1);
        g4o[gidx(L) >> 1] = make_float4(sre[p0], sim[p0], sre[p1], sim[p1]);
    }
}

// ---------------- overlap reduction (single kernel, last-block trick) ------
__global__ __launch_bounds__(256) void reduce_kernel(
    const float2* __restrict__ states, double* __restrict__ acc,
    unsigned* __restrict__ cnt, float* __restrict__ out)
{
    int t = threadIdx.x;
    const float2* s1 = states;
    const float2* s2 = states + NSTATE;
    double ar = 0.0, ai = 0.0;
    int base = blockIdx.x * 1024;
#pragma unroll
    for (int k = 0; k < 4; ++k) {
        int i = base + t + k * 256;
        float2 p1 = s1[i], p2 = s2[i];
        ar += (double)p2.x * p1.x + (double)p2.y * p1.y;
        ai += (double)p2.x * p1.y - (double)p2.y * p1.x;
    }
    for (int o = 32; o > 0; o >>= 1) {
        ar += __shfl_down(ar, o, 64);
        ai += __shfl_down(ai, o, 64);
    }
    __shared__ double wr[4], wi[4];
    int lane = t & 63, w = t >> 6;
    if (lane == 0) { wr[w] = ar; wi[w] = ai; }
    __syncthreads();
    if (t == 0) {
        double br = wr[0] + wr[1] + wr[2] + wr[3];
        double bi = wi[0] + wi[1] + wi[2] + wi[3];
        atomicAdd(&acc[0], br);
        atomicAdd(&acc[1], bi);
        __threadfence();
        unsigned old = atomicAdd(cnt, 1u);
        if (old == gridDim.x - 1) {
            double fr = atomicAdd(&acc[0], 0.0);
            double fi = atomicAdd(&acc[1], 0.0);
            out[0] = (float)(fr * fr + fi * fi);
        }
    }
}

// ---------------- launch ----------------------------------------------------
extern "C" void kernel_launch(void* const* d_in, const int* in_sizes, int n_in,
                              void* d_out, int out_size, void* d_ws, size_t ws_size,
                              hipStream_t stream)
{
    const float* x1 = (const float*)d_in[0];
    const float* x2 = (const float*)d_in[1];
    const float* iscale = (const float*)d_in[2];
    const float* var = (const float*)d_in[3];
    float* out = (float*)d_out;

    // ws layout: [0,6912) U; [8192,8208) acc (2 doubles); [8208,8212) cnt;
    // [16384, 16384+4MB) statevectors.
    float2*   U   = (float2*)d_ws;
    double*   acc = (double*)((char*)d_ws + 8192);
    unsigned* cnt = (unsigned*)((char*)d_ws + 8208);
    float2*   states = (float2*)((char*)d_ws + 16384);

    setup_kernel<<<1, 256, 0, stream>>>(x1, x2, iscale, var, U);

    dim3 grid(2 * NCHUNK), block(TPB);
    // args: setB, prev_layer, do_cz, next_layer, do_init, acc, cnt, zero_acc
    pass_kernel<<<grid, block, 0, stream>>>(states, U, 0, -1, 0, 0, 1, acc, cnt, 0);
    pass_kernel<<<grid, block, 0, stream>>>(states, U, 1, 0, 1, 1, 0, acc, cnt, 0);
    pass_kernel<<<grid, block, 0, stream>>>(states, U, 0, 1, 1, 2, 0, acc, cnt, 0);
    pass_kernel<<<grid, block, 0, stream>>>(states, U, 1, 2, 1, 3, 0, acc, cnt, 0);
    pass_kernel<<<grid, block, 0, stream>>>(states, U, 0, 3, 1, 4, 0, acc, cnt, 0);
    pass_kernel<<<grid, block, 0, stream>>>(states, U, 1, 4, 1, 5, 0, acc, cnt, 0);
    pass_kernel<<<grid, block, 0, stream>>>(states, U, 0, 5, 1, -1, 0, acc, cnt, 1);

    reduce_kernel<<<NSTATE / 1024, 256, 0, stream>>>(states, acc, cnt, out);
}